// Round 1
// baseline (635.605 us; speedup 1.0000x reference)
//
#include <hip/hip_runtime.h>

// ResidualGNNLayer: h = x@W; agg = segsum(h[src]*norm[src], dst)*norm + h*norm^2 + b;
// out = LayerNorm(x + agg) * gamma + beta.   N=100000, E=1600000, D=256, fp32.

#define D_DIM 256
#define SCAN_BLK 1024

// ---------------- small utility kernels ----------------
__global__ void zero_ints(int* __restrict__ p, int n) {
    int i = blockIdx.x * blockDim.x + threadIdx.x;
    if (i < n) p[i] = 0;
}

__global__ void deg_hist(const int* __restrict__ dst, int E, int* __restrict__ deg) {
    int i = blockIdx.x * blockDim.x + threadIdx.x;
    if (i < E) atomicAdd(&deg[dst[i]], 1);
}

// per-block exclusive scan of deg -> partial, block totals -> bsum
__global__ void scan1(const int* __restrict__ deg, int N,
                      int* __restrict__ partial, int* __restrict__ bsum) {
    __shared__ int s[SCAN_BLK];
    int t = threadIdx.x;
    int i = blockIdx.x * SCAN_BLK + t;
    int v = (i < N) ? deg[i] : 0;
    s[t] = v;
    __syncthreads();
    for (int off = 1; off < SCAN_BLK; off <<= 1) {
        int add = (t >= off) ? s[t - off] : 0;
        __syncthreads();
        s[t] += add;
        __syncthreads();
    }
    if (i < N) partial[i] = s[t] - v;              // exclusive
    if (t == SCAN_BLK - 1) bsum[blockIdx.x] = s[t]; // inclusive total
}

// single-block exclusive scan of block sums (nb <= 1024)
__global__ void scan2(int* __restrict__ bsum, int nb) {
    __shared__ int s[SCAN_BLK];
    int t = threadIdx.x;
    int v = (t < nb) ? bsum[t] : 0;
    s[t] = v;
    __syncthreads();
    for (int off = 1; off < SCAN_BLK; off <<= 1) {
        int add = (t >= off) ? s[t - off] : 0;
        __syncthreads();
        s[t] += add;
        __syncthreads();
    }
    if (t < nb) bsum[t] = s[t] - v; // exclusive, in place
}

// finalize: row_ptr, cursor copy, norm = rsqrt(deg+1)
__global__ void scan3(const int* __restrict__ partial, const int* __restrict__ bsum,
                      const int* __restrict__ deg, int N, int E,
                      int* __restrict__ row_ptr, int* __restrict__ cursor,
                      float* __restrict__ nrm) {
    int i = blockIdx.x * blockDim.x + threadIdx.x;
    if (i < N) {
        int rp = partial[i] + bsum[i / SCAN_BLK];
        row_ptr[i] = rp;
        cursor[i]  = rp;
        nrm[i] = rsqrtf((float)deg[i] + 1.0f);
    }
    if (i == N) row_ptr[N] = E;
}

__global__ void fill_csr(const int* __restrict__ src, const int* __restrict__ dst, int E,
                         int* __restrict__ cursor, int* __restrict__ srcs) {
    int i = blockIdx.x * blockDim.x + threadIdx.x;
    if (i < E) {
        int pos = atomicAdd(&cursor[dst[i]], 1);
        srcs[pos] = src[i];
    }
}

// ---------------- fp32 GEMM: H = X @ W  (MxK * KxN, K=N=256) ----------------
#define BM 64
#define BN 64
#define BK 16
__global__ __launch_bounds__(256) void gemm_f32(const float* __restrict__ X,
                                                const float* __restrict__ W,
                                                float* __restrict__ H, int M) {
    __shared__ float As[BK][BM + 4]; // stride 68 floats: 16B-aligned rows, spread banks
    __shared__ float Bs[BK][BN + 4];

    const int tx = threadIdx.x;      // 0..15
    const int ty = threadIdx.y;      // 0..15
    const int t  = ty * 16 + tx;
    const int m0 = blockIdx.x * BM;
    const int n0 = blockIdx.y * BN;

    // A-load mapping: thread t loads float4 at (m = t>>2, k = (t&3)*4)
    const int ma = t >> 2, ka = (t & 3) * 4;
    // B-load mapping: thread t loads float4 at (k = t>>4, n = (t&15)*4)
    const int kb = t >> 4, nb = (t & 15) * 4;

    float acc[4][4];
#pragma unroll
    for (int i = 0; i < 4; ++i)
#pragma unroll
        for (int j = 0; j < 4; ++j) acc[i][j] = 0.f;

    for (int kk = 0; kk < D_DIM; kk += BK) {
        // load A tile 64x16
        float4 a4 = make_float4(0.f, 0.f, 0.f, 0.f);
        if (m0 + ma < M)
            a4 = *reinterpret_cast<const float4*>(&X[(size_t)(m0 + ma) * D_DIM + kk + ka]);
        // load B tile 16x64 (W is 256x256, always in range)
        float4 b4 = *reinterpret_cast<const float4*>(&W[(size_t)(kk + kb) * D_DIM + n0 + nb]);

        __syncthreads();
        As[ka + 0][ma] = a4.x;
        As[ka + 1][ma] = a4.y;
        As[ka + 2][ma] = a4.z;
        As[ka + 3][ma] = a4.w;
        *reinterpret_cast<float4*>(&Bs[kb][nb]) = b4;
        __syncthreads();

#pragma unroll
        for (int k = 0; k < BK; ++k) {
            float4 av = *reinterpret_cast<const float4*>(&As[k][ty * 4]);
            float4 bv = *reinterpret_cast<const float4*>(&Bs[k][tx * 4]);
            float a[4] = {av.x, av.y, av.z, av.w};
            float b[4] = {bv.x, bv.y, bv.z, bv.w};
#pragma unroll
            for (int i = 0; i < 4; ++i)
#pragma unroll
                for (int j = 0; j < 4; ++j) acc[i][j] = fmaf(a[i], b[j], acc[i][j]);
        }
    }

#pragma unroll
    for (int i = 0; i < 4; ++i) {
        int row = m0 + ty * 4 + i;
        if (row < M) {
            float4 o = make_float4(acc[i][0], acc[i][1], acc[i][2], acc[i][3]);
            *reinterpret_cast<float4*>(&H[(size_t)row * D_DIM + n0 + tx * 4]) = o;
        }
    }
}

// ---------------- fused aggregate + residual + LayerNorm ----------------
// one wave (64 lanes) per destination node; each lane owns float4 of the row
__global__ __launch_bounds__(256) void aggregate_ln(
    const float* __restrict__ X, const float* __restrict__ H,
    const int* __restrict__ row_ptr, const int* __restrict__ srcs,
    const float* __restrict__ nrm, const float* __restrict__ bvec,
    const float* __restrict__ gamma, const float* __restrict__ beta,
    float* __restrict__ out, int N) {
    const int wave = (blockIdx.x * blockDim.x + threadIdx.x) >> 6;
    const int lane = threadIdx.x & 63;
    if (wave >= N) return;
    const int i = wave;

    const float4* Hv = reinterpret_cast<const float4*>(H);

    float4 acc = make_float4(0.f, 0.f, 0.f, 0.f);
    const int beg = row_ptr[i], end = row_ptr[i + 1];
    for (int e = beg; e < end; ++e) {
        int s = srcs[e];
        float ns = nrm[s];
        float4 hv = Hv[(size_t)s * 64 + lane];
        acc.x = fmaf(hv.x, ns, acc.x);
        acc.y = fmaf(hv.y, ns, acc.y);
        acc.z = fmaf(hv.z, ns, acc.z);
        acc.w = fmaf(hv.w, ns, acc.w);
    }

    const float ni = nrm[i];
    const float nii = ni * ni;
    float4 hv = Hv[(size_t)i * 64 + lane];
    float4 xv = reinterpret_cast<const float4*>(X)[(size_t)i * 64 + lane];
    float4 bv = reinterpret_cast<const float4*>(bvec)[lane];

    float4 y;
    y.x = xv.x + acc.x * ni + hv.x * nii + bv.x;
    y.y = xv.y + acc.y * ni + hv.y * nii + bv.y;
    y.z = xv.z + acc.z * ni + hv.z * nii + bv.z;
    y.w = xv.w + acc.w * ni + hv.w * nii + bv.w;

    // wave-wide LayerNorm over 256 values
    float s1 = y.x + y.y + y.z + y.w;
    float s2 = y.x * y.x + y.y * y.y + y.z * y.z + y.w * y.w;
#pragma unroll
    for (int off = 32; off > 0; off >>= 1) {
        s1 += __shfl_xor(s1, off);
        s2 += __shfl_xor(s2, off);
    }
    const float mean = s1 * (1.0f / 256.0f);
    const float var  = s2 * (1.0f / 256.0f) - mean * mean;
    const float rstd = rsqrtf(var + 1e-3f);

    float4 gv = reinterpret_cast<const float4*>(gamma)[lane];
    float4 be = reinterpret_cast<const float4*>(beta)[lane];
    float4 o;
    o.x = gv.x * (y.x - mean) * rstd + be.x;
    o.y = gv.y * (y.y - mean) * rstd + be.y;
    o.z = gv.z * (y.z - mean) * rstd + be.z;
    o.w = gv.w * (y.w - mean) * rstd + be.w;
    reinterpret_cast<float4*>(out)[(size_t)i * 64 + lane] = o;
}

// ---------------- launch ----------------
extern "C" void kernel_launch(void* const* d_in, const int* in_sizes, int n_in,
                              void* d_out, int out_size, void* d_ws, size_t ws_size,
                              hipStream_t stream) {
    const float* x     = (const float*)d_in[0];
    const int*   ei    = (const int*)d_in[1];
    const float* W     = (const float*)d_in[2];
    const float* bvec  = (const float*)d_in[3];
    const float* gamma = (const float*)d_in[4];
    const float* beta  = (const float*)d_in[5];
    float*       out   = (float*)d_out;

    const int D = in_sizes[3];          // 256
    const int N = in_sizes[0] / D;      // 100000
    const int E = in_sizes[1] / 2;      // 1600000
    const int* src = ei;
    const int* dst = ei + E;

    // workspace layout
    char* w = (char*)d_ws;
    size_t off = 0;
    auto alloc = [&](size_t bytes) -> void* {
        void* p = w + off;
        off = (off + bytes + 255) & ~(size_t)255;
        return p;
    };
    float* H       = (float*)alloc((size_t)N * D * sizeof(float));
    float* nrm     = (float*)alloc((size_t)N * sizeof(float));
    int*   deg     = (int*)alloc((size_t)N * sizeof(int));
    int*   partial = (int*)alloc((size_t)N * sizeof(int));
    int*   bsum    = (int*)alloc((size_t)SCAN_BLK * sizeof(int));
    int*   row_ptr = (int*)alloc((size_t)(N + 1) * sizeof(int));
    int*   cursor  = (int*)alloc((size_t)N * sizeof(int));
    int*   srcs    = (int*)alloc((size_t)E * sizeof(int));
    (void)ws_size;

    const int NB = (N + SCAN_BLK - 1) / SCAN_BLK; // 98

    zero_ints<<<(N + 255) / 256, 256, 0, stream>>>(deg, N);
    deg_hist<<<(E + 255) / 256, 256, 0, stream>>>(dst, E, deg);
    scan1<<<NB, SCAN_BLK, 0, stream>>>(deg, N, partial, bsum);
    scan2<<<1, SCAN_BLK, 0, stream>>>(bsum, NB);
    scan3<<<(N + 1 + 255) / 256, 256, 0, stream>>>(partial, bsum, deg, N, E,
                                                   row_ptr, cursor, nrm);
    fill_csr<<<(E + 255) / 256, 256, 0, stream>>>(src, dst, E, cursor, srcs);

    dim3 ggrid((N + BM - 1) / BM, D / BN);
    dim3 gblk(16, 16);
    gemm_f32<<<ggrid, gblk, 0, stream>>>(x, W, H, N);

    int agg_blocks = (N + 3) / 4; // 4 waves per 256-thread block
    aggregate_ln<<<agg_blocks, 256, 0, stream>>>(x, H, row_ptr, srcs, nrm, bvec,
                                                 gamma, beta, out, N);
}

// Round 2
// 395.922 us; speedup vs baseline: 1.6054x; 1.6054x over previous
//
#include <hip/hip_runtime.h>

// ResidualGNNLayer: h = x@W (bf16 MFMA); agg = segsum(h[src]*nrm[src], dst)*nrm
//                   + h*nrm^2 + b; out = LayerNorm(x + agg)*gamma + beta.
// N=100000, E=1600000, D=256, fp32 in/out; h kept in bf16.

#define D_DIM 256
#define SCAN_BLK 1024

typedef __attribute__((ext_vector_type(8))) short short8;
typedef __attribute__((ext_vector_type(4))) float f32x4;

__device__ __forceinline__ unsigned short f2bf(float f) {
    unsigned int u = __builtin_bit_cast(unsigned int, f);
    u = (u + 0x7fffu + ((u >> 16) & 1u)) >> 16;   // RNE
    return (unsigned short)u;
}
__device__ __forceinline__ float bf2f(unsigned short u) {
    return __builtin_bit_cast(float, (unsigned int)u << 16);
}

// ---------------- small utility kernels ----------------
__global__ void zero_ints(int* __restrict__ p, int n) {
    int i = blockIdx.x * blockDim.x + threadIdx.x;
    if (i < n) p[i] = 0;
}

__global__ void deg_hist(const int* __restrict__ dst, int E, int* __restrict__ deg) {
    int i = blockIdx.x * blockDim.x + threadIdx.x;
    if (i < E) atomicAdd(&deg[dst[i]], 1);
}

__global__ void scan1(const int* __restrict__ deg, int N,
                      int* __restrict__ partial, int* __restrict__ bsum) {
    __shared__ int s[SCAN_BLK];
    int t = threadIdx.x;
    int i = blockIdx.x * SCAN_BLK + t;
    int v = (i < N) ? deg[i] : 0;
    s[t] = v;
    __syncthreads();
    for (int off = 1; off < SCAN_BLK; off <<= 1) {
        int add = (t >= off) ? s[t - off] : 0;
        __syncthreads();
        s[t] += add;
        __syncthreads();
    }
    if (i < N) partial[i] = s[t] - v;
    if (t == SCAN_BLK - 1) bsum[blockIdx.x] = s[t];
}

__global__ void scan2(int* __restrict__ bsum, int nb) {
    __shared__ int s[SCAN_BLK];
    int t = threadIdx.x;
    int v = (t < nb) ? bsum[t] : 0;
    s[t] = v;
    __syncthreads();
    for (int off = 1; off < SCAN_BLK; off <<= 1) {
        int add = (t >= off) ? s[t - off] : 0;
        __syncthreads();
        s[t] += add;
        __syncthreads();
    }
    if (t < nb) bsum[t] = s[t] - v;
}

__global__ void scan3(const int* __restrict__ partial, const int* __restrict__ bsum,
                      const int* __restrict__ deg, int N, int E,
                      int* __restrict__ row_ptr, int* __restrict__ cursor,
                      float* __restrict__ nrm) {
    int i = blockIdx.x * blockDim.x + threadIdx.x;
    if (i < N) {
        int rp = partial[i] + bsum[i / SCAN_BLK];
        row_ptr[i] = rp;
        cursor[i]  = rp;
        nrm[i] = rsqrtf((float)deg[i] + 1.0f);
    }
    if (i == N) row_ptr[N] = E;
}

__global__ void fill_csr(const int* __restrict__ src, const int* __restrict__ dst, int E,
                         int* __restrict__ cursor, int* __restrict__ srcs) {
    int i = blockIdx.x * blockDim.x + threadIdx.x;
    if (i < E) {
        int pos = atomicAdd(&cursor[dst[i]], 1);
        srcs[pos] = src[i];
    }
}

// cast+transpose W (256x256 fp32, [k][n]) -> Wt bf16 [n][k]
__global__ void cast_wt(const float* __restrict__ W, unsigned short* __restrict__ Wt) {
    int t = blockIdx.x * blockDim.x + threadIdx.x;   // 65536 threads
    int k = t >> 8, n = t & 255;
    Wt[(size_t)n * D_DIM + k] = f2bf(W[(size_t)k * D_DIM + n]);
}

// ---------------- bf16 MFMA GEMM: Hb = bf16(X) @ W  ----------------
// 128x128 tile, BK=32, 256 threads = 4 waves in 2x2, each wave 64x64 out.
#define GBM 128
#define GBN 128
#define GBK 32
#define LDK 40   // padded LDS k-stride (shorts): 80 B, 16B-aligned, 2-way banks only

__global__ __launch_bounds__(256) void gemm_mfma(
    const float* __restrict__ X, const unsigned short* __restrict__ Wt,
    unsigned short* __restrict__ Hb, int M) {
    __shared__ unsigned short As[GBM * LDK];
    __shared__ unsigned short Bs[GBN * LDK];

    const int t    = threadIdx.x;
    const int lane = t & 63;
    const int wave = t >> 6;
    const int wr   = wave >> 1, wc = wave & 1;
    const int m0   = blockIdx.x * GBM, n0 = blockIdx.y * GBN;

    const int lm = t >> 2;          // 0..63
    const int lk = (t & 3) * 8;     // 0,8,16,24

    f32x4 acc[4][4];
#pragma unroll
    for (int mi = 0; mi < 4; ++mi)
#pragma unroll
        for (int ni = 0; ni < 4; ++ni) acc[mi][ni] = (f32x4){0.f, 0.f, 0.f, 0.f};

    const int ar0 = (m0 + lm      < M) ? (m0 + lm)      : (M - 1);
    const int ar1 = (m0 + lm + 64 < M) ? (m0 + lm + 64) : (M - 1);

    for (int kk = 0; kk < D_DIM; kk += GBK) {
        // global loads (A converted fp32->bf16 in flight)
        float4 a00 = *(const float4*)(X + (size_t)ar0 * D_DIM + kk + lk);
        float4 a01 = *(const float4*)(X + (size_t)ar0 * D_DIM + kk + lk + 4);
        float4 a10 = *(const float4*)(X + (size_t)ar1 * D_DIM + kk + lk);
        float4 a11 = *(const float4*)(X + (size_t)ar1 * D_DIM + kk + lk + 4);
        uint4  b0  = *(const uint4*)(Wt + (size_t)(n0 + lm)      * D_DIM + kk + lk);
        uint4  b1  = *(const uint4*)(Wt + (size_t)(n0 + lm + 64) * D_DIM + kk + lk);

        auto pack2 = [](float a, float b) {
            return (unsigned int)f2bf(a) | ((unsigned int)f2bf(b) << 16);
        };
        uint4 A0 = {pack2(a00.x, a00.y), pack2(a00.z, a00.w),
                    pack2(a01.x, a01.y), pack2(a01.z, a01.w)};
        uint4 A1 = {pack2(a10.x, a10.y), pack2(a10.z, a10.w),
                    pack2(a11.x, a11.y), pack2(a11.z, a11.w)};

        __syncthreads();
        *(uint4*)&As[(size_t)lm * LDK + lk]        = A0;
        *(uint4*)&As[(size_t)(lm + 64) * LDK + lk] = A1;
        *(uint4*)&Bs[(size_t)lm * LDK + lk]        = b0;
        *(uint4*)&Bs[(size_t)(lm + 64) * LDK + lk] = b1;
        __syncthreads();

        const int kp = (lane >> 4) * 8;
        short8 af[4], bfr[4];
#pragma unroll
        for (int mi = 0; mi < 4; ++mi)
            af[mi] = *(const short8*)&As[(size_t)(wr * 64 + mi * 16 + (lane & 15)) * LDK + kp];
#pragma unroll
        for (int ni = 0; ni < 4; ++ni)
            bfr[ni] = *(const short8*)&Bs[(size_t)(wc * 64 + ni * 16 + (lane & 15)) * LDK + kp];
#pragma unroll
        for (int mi = 0; mi < 4; ++mi)
#pragma unroll
            for (int ni = 0; ni < 4; ++ni)
                acc[mi][ni] = __builtin_amdgcn_mfma_f32_16x16x32_bf16(
                    af[mi], bfr[ni], acc[mi][ni], 0, 0, 0);
    }

    // store bf16 (D layout: col = lane&15, row = (lane>>4)*4 + r)
#pragma unroll
    for (int mi = 0; mi < 4; ++mi) {
#pragma unroll
        for (int r = 0; r < 4; ++r) {
            int row = m0 + wr * 64 + mi * 16 + (lane >> 4) * 4 + r;
            if (row < M) {
#pragma unroll
                for (int ni = 0; ni < 4; ++ni) {
                    int col = n0 + wc * 64 + ni * 16 + (lane & 15);
                    Hb[(size_t)row * D_DIM + col] = f2bf(acc[mi][ni][r]);
                }
            }
        }
    }
}

// ---------------- fused aggregate + residual + LayerNorm ----------------
// one wave per node; lane owns 4 bf16 (8 B) of each gathered row
__global__ __launch_bounds__(256) void aggregate_ln(
    const float* __restrict__ X, const unsigned short* __restrict__ Hb,
    const int* __restrict__ row_ptr, const int* __restrict__ srcs,
    const float* __restrict__ nrm, const float* __restrict__ bvec,
    const float* __restrict__ gamma, const float* __restrict__ beta,
    float* __restrict__ out, int N) {
    const int wave = (blockIdx.x * blockDim.x + threadIdx.x) >> 6;
    const int lane = threadIdx.x & 63;
    if (wave >= N) return;
    const int i = wave;

    float ax = 0.f, ay = 0.f, az = 0.f, aw = 0.f;
    const int beg = row_ptr[i], end = row_ptr[i + 1];

    auto ldrow = [&](int s) -> ushort4 {
        return *((const ushort4*)(Hb + (size_t)s * D_DIM) + lane);
    };
    auto accum = [&](ushort4 h, float w) {
        ax = fmaf(bf2f(h.x), w, ax);
        ay = fmaf(bf2f(h.y), w, ay);
        az = fmaf(bf2f(h.z), w, az);
        aw = fmaf(bf2f(h.w), w, aw);
    };

    int e = beg;
    for (; e + 4 <= end; e += 4) {
        int s0 = __builtin_amdgcn_readfirstlane(srcs[e]);
        int s1 = __builtin_amdgcn_readfirstlane(srcs[e + 1]);
        int s2 = __builtin_amdgcn_readfirstlane(srcs[e + 2]);
        int s3 = __builtin_amdgcn_readfirstlane(srcs[e + 3]);
        ushort4 h0 = ldrow(s0), h1 = ldrow(s1), h2 = ldrow(s2), h3 = ldrow(s3);
        float w0 = nrm[s0], w1 = nrm[s1], w2 = nrm[s2], w3 = nrm[s3];
        accum(h0, w0); accum(h1, w1); accum(h2, w2); accum(h3, w3);
    }
    for (; e < end; ++e) {
        int s = __builtin_amdgcn_readfirstlane(srcs[e]);
        accum(ldrow(s), nrm[s]);
    }

    const float ni  = nrm[i];
    const float nii = ni * ni;
    ushort4 hv = ldrow(i);
    float4  xv = reinterpret_cast<const float4*>(X)[(size_t)i * 64 + lane];
    float4  bv = reinterpret_cast<const float4*>(bvec)[lane];

    float4 y;
    y.x = xv.x + ax * ni + bf2f(hv.x) * nii + bv.x;
    y.y = xv.y + ay * ni + bf2f(hv.y) * nii + bv.y;
    y.z = xv.z + az * ni + bf2f(hv.z) * nii + bv.z;
    y.w = xv.w + aw * ni + bf2f(hv.w) * nii + bv.w;

    float s1 = y.x + y.y + y.z + y.w;
    float s2 = y.x * y.x + y.y * y.y + y.z * y.z + y.w * y.w;
#pragma unroll
    for (int off = 32; off > 0; off >>= 1) {
        s1 += __shfl_xor(s1, off);
        s2 += __shfl_xor(s2, off);
    }
    const float mean = s1 * (1.0f / 256.0f);
    const float var  = s2 * (1.0f / 256.0f) - mean * mean;
    const float rstd = rsqrtf(var + 1e-3f);

    float4 gv = reinterpret_cast<const float4*>(gamma)[lane];
    float4 be = reinterpret_cast<const float4*>(beta)[lane];
    float4 o;
    o.x = gv.x * (y.x - mean) * rstd + be.x;
    o.y = gv.y * (y.y - mean) * rstd + be.y;
    o.z = gv.z * (y.z - mean) * rstd + be.z;
    o.w = gv.w * (y.w - mean) * rstd + be.w;
    reinterpret_cast<float4*>(out)[(size_t)i * 64 + lane] = o;
}

// ---------------- launch ----------------
extern "C" void kernel_launch(void* const* d_in, const int* in_sizes, int n_in,
                              void* d_out, int out_size, void* d_ws, size_t ws_size,
                              hipStream_t stream) {
    const float* x     = (const float*)d_in[0];
    const int*   ei    = (const int*)d_in[1];
    const float* W     = (const float*)d_in[2];
    const float* bvec  = (const float*)d_in[3];
    const float* gamma = (const float*)d_in[4];
    const float* beta  = (const float*)d_in[5];
    float*       out   = (float*)d_out;

    const int D = in_sizes[3];          // 256
    const int N = in_sizes[0] / D;      // 100000
    const int E = in_sizes[1] / 2;      // 1600000
    const int* src = ei;
    const int* dst = ei + E;

    char* w = (char*)d_ws;
    size_t off = 0;
    auto alloc = [&](size_t bytes) -> void* {
        void* p = w + off;
        off = (off + bytes + 255) & ~(size_t)255;
        return p;
    };
    unsigned short* Hb      = (unsigned short*)alloc((size_t)N * D * sizeof(unsigned short));
    unsigned short* Wt      = (unsigned short*)alloc((size_t)D * D * sizeof(unsigned short));
    float*          nrm     = (float*)alloc((size_t)N * sizeof(float));
    int*            deg     = (int*)alloc((size_t)N * sizeof(int));
    int*            partial = (int*)alloc((size_t)N * sizeof(int));
    int*            bsum    = (int*)alloc((size_t)SCAN_BLK * sizeof(int));
    int*            row_ptr = (int*)alloc((size_t)(N + 1) * sizeof(int));
    int*            cursor  = (int*)alloc((size_t)N * sizeof(int));
    int*            srcs    = (int*)alloc((size_t)E * sizeof(int));
    (void)ws_size;

    const int NB = (N + SCAN_BLK - 1) / SCAN_BLK;

    cast_wt<<<(D * D + 255) / 256, 256, 0, stream>>>(W, Wt);
    zero_ints<<<(N + 255) / 256, 256, 0, stream>>>(deg, N);
    deg_hist<<<(E + 255) / 256, 256, 0, stream>>>(dst, E, deg);
    scan1<<<NB, SCAN_BLK, 0, stream>>>(deg, N, partial, bsum);
    scan2<<<1, SCAN_BLK, 0, stream>>>(bsum, NB);
    scan3<<<(N + 1 + 255) / 256, 256, 0, stream>>>(partial, bsum, deg, N, E,
                                                   row_ptr, cursor, nrm);
    fill_csr<<<(E + 255) / 256, 256, 0, stream>>>(src, dst, E, cursor, srcs);

    dim3 ggrid((N + GBM - 1) / GBM, D / GBN);
    gemm_mfma<<<ggrid, 256, 0, stream>>>(x, Wt, Hb, N);

    int agg_blocks = (N + 3) / 4;  // 4 waves per 256-thread block
    aggregate_ln<<<agg_blocks, 256, 0, stream>>>(x, Hb, row_ptr, srcs, nrm, bvec,
                                                 gamma, beta, out, N);
}

// Round 5
// 387.609 us; speedup vs baseline: 1.6398x; 1.0214x over previous
//
#include <hip/hip_runtime.h>

// ResidualGNNLayer: h = x@W (bf16 MFMA, W fully LDS-resident); agg = segsum(...)
// + h*nrm^2 + b; out = LayerNorm(x + agg)*gamma + beta.
// N=100000, E=1600000, D=256, fp32 in/out; h stored bf16.

#define D_DIM 256
#define SCAN_BLK 1024

typedef __attribute__((ext_vector_type(8))) short short8;
typedef __attribute__((ext_vector_type(4))) float f32x4;

__device__ __forceinline__ unsigned short f2bf(float f) {
    unsigned int u = __builtin_bit_cast(unsigned int, f);
    u = (u + 0x7fffu + ((u >> 16) & 1u)) >> 16;   // RNE
    return (unsigned short)u;
}
__device__ __forceinline__ float bf2f(unsigned short u) {
    return __builtin_bit_cast(float, (unsigned int)u << 16);
}
__device__ __forceinline__ unsigned int pack2(float a, float b) {
    return (unsigned int)f2bf(a) | ((unsigned int)f2bf(b) << 16);
}

// ---------------- small utility kernels ----------------
__global__ void zero_ints(int* __restrict__ p, int n) {
    int i = blockIdx.x * blockDim.x + threadIdx.x;
    if (i < n) p[i] = 0;
}

__global__ void deg_hist(const int* __restrict__ dst, int E, int* __restrict__ deg) {
    int i = blockIdx.x * blockDim.x + threadIdx.x;
    if (i < E) atomicAdd(&deg[dst[i]], 1);
}

__global__ void scan1(const int* __restrict__ deg, int N,
                      int* __restrict__ partial, int* __restrict__ bsum) {
    __shared__ int s[SCAN_BLK];
    int t = threadIdx.x;
    int i = blockIdx.x * SCAN_BLK + t;
    int v = (i < N) ? deg[i] : 0;
    s[t] = v;
    __syncthreads();
    for (int off = 1; off < SCAN_BLK; off <<= 1) {
        int add = (t >= off) ? s[t - off] : 0;
        __syncthreads();
        s[t] += add;
        __syncthreads();
    }
    if (i < N) partial[i] = s[t] - v;
    if (t == SCAN_BLK - 1) bsum[blockIdx.x] = s[t];
}

__global__ void scan2(int* __restrict__ bsum, int nb) {
    __shared__ int s[SCAN_BLK];
    int t = threadIdx.x;
    int v = (t < nb) ? bsum[t] : 0;
    s[t] = v;
    __syncthreads();
    for (int off = 1; off < SCAN_BLK; off <<= 1) {
        int add = (t >= off) ? s[t - off] : 0;
        __syncthreads();
        s[t] += add;
        __syncthreads();
    }
    if (t < nb) bsum[t] = s[t] - v;
}

__global__ void scan3(const int* __restrict__ partial, const int* __restrict__ bsum,
                      const int* __restrict__ deg, int N, int E,
                      int* __restrict__ row_ptr, int* __restrict__ cursor,
                      float* __restrict__ nrm) {
    int i = blockIdx.x * blockDim.x + threadIdx.x;
    if (i < N) {
        int rp = partial[i] + bsum[i / SCAN_BLK];
        row_ptr[i] = rp;
        cursor[i]  = rp;
        nrm[i] = rsqrtf((float)deg[i] + 1.0f);
    }
    if (i == N) row_ptr[N] = E;
}

__global__ void fill_csr(const int* __restrict__ src, const int* __restrict__ dst, int E,
                         int* __restrict__ cursor, int* __restrict__ srcs) {
    int i = blockIdx.x * blockDim.x + threadIdx.x;
    if (i < E) {
        int pos = atomicAdd(&cursor[dst[i]], 1);
        srcs[pos] = src[i];
    }
}

// cast+transpose W (256x256 fp32, [k][n]) -> Wt bf16 [n][k]
__global__ void cast_wt(const float* __restrict__ W, unsigned short* __restrict__ Wt) {
    int t = blockIdx.x * blockDim.x + threadIdx.x;
    int k = t >> 8, n = t & 255;
    Wt[(size_t)n * D_DIM + k] = f2bf(W[(size_t)k * D_DIM + n]);
}

// ---------------- bf16 MFMA GEMM: Hb = bf16(X) @ W ----------------
// 128(M) x 256(N=all) tile; Wt fully in LDS (XOR-swizzled, loaded once);
// A double-buffered with in-flight prefetch. 512 thr = 8 waves (2x4), wave=64x64.
#define GBM 128
#define LDA 40      // padded A k-stride (shorts)

__global__ __launch_bounds__(512) void gemm_mfma(
    const float* __restrict__ X, const unsigned short* __restrict__ Wt,
    unsigned short* __restrict__ Hb, int M) {
    __shared__ unsigned short WtL[256 * 256];     // [n][k], k XOR-swizzled, 128 KiB
    __shared__ unsigned short As[2][GBM * LDA];   // 20 KiB

    const int t    = threadIdx.x;
    const int lane = t & 63;
    const int wave = t >> 6;
    const int wr   = wave >> 2, wc = wave & 3;    // 2 x 4 wave grid
    const int m0   = blockIdx.x * GBM;

    // ---- Wt prologue: whole 256x256 bf16 into LDS, swizzled ----
    // 8192 uint4 total; 16 per thread: row n = u>>5, k-chunk kc = (u&31)*8.
#pragma unroll
    for (int c = 0; c < 16; ++c) {
        int u  = c * 512 + t;
        int n  = u >> 5;
        int kc = (u & 31) * 8;
        int ks = kc ^ ((n & 15) << 3); // 16-B-chunk XOR swizzle within row
        *(uint4*)&WtL[n * 256 + ks] = *(const uint4*)(Wt + (size_t)n * 256 + kc);
    }

    // ---- A staging mapping: thread -> (row 0..127, k-chunk of 8) ----
    const int arow = t >> 2;
    const int akc  = (t & 3) * 8;
    const int xr   = (m0 + arow < M) ? (m0 + arow) : (M - 1);
    const float* xp = X + (size_t)xr * D_DIM;

    {   // stage k-step 0 into buf 0
        float4 a0 = *(const float4*)(xp + akc);
        float4 a1 = *(const float4*)(xp + akc + 4);
        uint4 A = {pack2(a0.x, a0.y), pack2(a0.z, a0.w),
                   pack2(a1.x, a1.y), pack2(a1.z, a1.w)};
        *(uint4*)&As[0][arow * LDA + akc] = A;
    }
    __syncthreads();

    f32x4 acc[4][4];
#pragma unroll
    for (int mi = 0; mi < 4; ++mi)
#pragma unroll
        for (int ni = 0; ni < 4; ++ni) acc[mi][ni] = (f32x4){0.f, 0.f, 0.f, 0.f};

    const int kp = (lane >> 4) * 8;

    for (int s = 0; s < 8; ++s) {
        float4 a0, a1;
        if (s < 7) {   // prefetch next A tile (global, in flight during MFMA)
            a0 = *(const float4*)(xp + (s + 1) * 32 + akc);
            a1 = *(const float4*)(xp + (s + 1) * 32 + akc + 4);
        }

        short8 af[4], bfr[4];
#pragma unroll
        for (int mi = 0; mi < 4; ++mi)
            af[mi] = *(const short8*)&As[s & 1][(wr * 64 + mi * 16 + (lane & 15)) * LDA + kp];
#pragma unroll
        for (int ni = 0; ni < 4; ++ni) {
            int n  = wc * 64 + ni * 16 + (lane & 15);
            int k  = s * 32 + kp;
            int ks = k ^ ((n & 15) << 3);
            bfr[ni] = *(const short8*)&WtL[n * 256 + ks];
        }
#pragma unroll
        for (int mi = 0; mi < 4; ++mi)
#pragma unroll
            for (int ni = 0; ni < 4; ++ni)
                acc[mi][ni] = __builtin_amdgcn_mfma_f32_16x16x32_bf16(
                    af[mi], bfr[ni], acc[mi][ni], 0, 0, 0);

        if (s < 7) {
            uint4 A = {pack2(a0.x, a0.y), pack2(a0.z, a0.w),
                       pack2(a1.x, a1.y), pack2(a1.z, a1.w)};
            *(uint4*)&As[(s + 1) & 1][arow * LDA + akc] = A;
            __syncthreads();
        }
    }

    // store bf16 (C layout: col = lane&15, row = (lane>>4)*4 + r)
#pragma unroll
    for (int mi = 0; mi < 4; ++mi) {
#pragma unroll
        for (int r = 0; r < 4; ++r) {
            int row = m0 + wr * 64 + mi * 16 + (lane >> 4) * 4 + r;
            if (row < M) {
#pragma unroll
                for (int ni = 0; ni < 4; ++ni) {
                    int col = wc * 64 + ni * 16 + (lane & 15);
                    Hb[(size_t)row * D_DIM + col] = f2bf(acc[mi][ni][r]);
                }
            }
        }
    }
}

// ---------------- fused aggregate + residual + LayerNorm ----------------
// one wave per node; lane owns 4 bf16 (8 B) of each gathered row.
// Streams (x, out) use non-temporal access to keep Hb L3-resident.
__global__ __launch_bounds__(256) void aggregate_ln(
    const float* __restrict__ X, const unsigned short* __restrict__ Hb,
    const int* __restrict__ row_ptr, const int* __restrict__ srcs,
    const float* __restrict__ nrm, const float* __restrict__ bvec,
    const float* __restrict__ gamma, const float* __restrict__ beta,
    float* __restrict__ out, int N) {
    const int wave = (blockIdx.x * blockDim.x + threadIdx.x) >> 6;
    const int lane = threadIdx.x & 63;
    if (wave >= N) return;
    const int i = wave;

    float ax = 0.f, ay = 0.f, az = 0.f, aw = 0.f;
    const int beg = row_ptr[i], end = row_ptr[i + 1];

    auto ldrow = [&](int s) -> ushort4 {
        return *((const ushort4*)(Hb + (size_t)s * D_DIM) + lane);
    };
    auto accum = [&](ushort4 h, float w) {
        ax = fmaf(bf2f(h.x), w, ax);
        ay = fmaf(bf2f(h.y), w, ay);
        az = fmaf(bf2f(h.z), w, az);
        aw = fmaf(bf2f(h.w), w, aw);
    };

    int e = beg;
    for (; e + 4 <= end; e += 4) {
        int s0 = __builtin_amdgcn_readfirstlane(srcs[e]);
        int s1 = __builtin_amdgcn_readfirstlane(srcs[e + 1]);
        int s2 = __builtin_amdgcn_readfirstlane(srcs[e + 2]);
        int s3 = __builtin_amdgcn_readfirstlane(srcs[e + 3]);
        ushort4 h0 = ldrow(s0), h1 = ldrow(s1), h2 = ldrow(s2), h3 = ldrow(s3);
        float w0 = nrm[s0], w1 = nrm[s1], w2 = nrm[s2], w3 = nrm[s3];
        accum(h0, w0); accum(h1, w1); accum(h2, w2); accum(h3, w3);
    }
    for (; e < end; ++e) {
        int s = __builtin_amdgcn_readfirstlane(srcs[e]);
        accum(ldrow(s), nrm[s]);
    }

    const float ni  = nrm[i];
    const float nii = ni * ni;
    ushort4 hv = ldrow(i);
    f32x4   xv = __builtin_nontemporal_load(
                     reinterpret_cast<const f32x4*>(X) + (size_t)i * 64 + lane);
    float4  bv = reinterpret_cast<const float4*>(bvec)[lane];

    float4 y;
    y.x = xv.x + ax * ni + bf2f(hv.x) * nii + bv.x;
    y.y = xv.y + ay * ni + bf2f(hv.y) * nii + bv.y;
    y.z = xv.z + az * ni + bf2f(hv.z) * nii + bv.z;
    y.w = xv.w + aw * ni + bf2f(hv.w) * nii + bv.w;

    float s1 = y.x + y.y + y.z + y.w;
    float s2 = y.x * y.x + y.y * y.y + y.z * y.z + y.w * y.w;
#pragma unroll
    for (int off = 32; off > 0; off >>= 1) {
        s1 += __shfl_xor(s1, off);
        s2 += __shfl_xor(s2, off);
    }
    const float mean = s1 * (1.0f / 256.0f);
    const float var  = s2 * (1.0f / 256.0f) - mean * mean;
    const float rstd = rsqrtf(var + 1e-3f);

    float4 gv = reinterpret_cast<const float4*>(gamma)[lane];
    float4 be = reinterpret_cast<const float4*>(beta)[lane];
    f32x4 o;
    o.x = gv.x * (y.x - mean) * rstd + be.x;
    o.y = gv.y * (y.y - mean) * rstd + be.y;
    o.z = gv.z * (y.z - mean) * rstd + be.z;
    o.w = gv.w * (y.w - mean) * rstd + be.w;
    __builtin_nontemporal_store(o, reinterpret_cast<f32x4*>(out) + (size_t)i * 64 + lane);
}

// ---------------- launch ----------------
extern "C" void kernel_launch(void* const* d_in, const int* in_sizes, int n_in,
                              void* d_out, int out_size, void* d_ws, size_t ws_size,
                              hipStream_t stream) {
    const float* x     = (const float*)d_in[0];
    const int*   ei    = (const int*)d_in[1];
    const float* W     = (const float*)d_in[2];
    const float* bvec  = (const float*)d_in[3];
    const float* gamma = (const float*)d_in[4];
    const float* beta  = (const float*)d_in[5];
    float*       out   = (float*)d_out;

    const int D = in_sizes[3];          // 256
    const int N = in_sizes[0] / D;      // 100000
    const int E = in_sizes[1] / 2;      // 1600000
    const int* src = ei;
    const int* dst = ei + E;

    char* w = (char*)d_ws;
    size_t off = 0;
    auto alloc = [&](size_t bytes) -> void* {
        void* p = w + off;
        off = (off + bytes + 255) & ~(size_t)255;
        return p;
    };
    unsigned short* Hb      = (unsigned short*)alloc((size_t)N * D * sizeof(unsigned short));
    unsigned short* Wt      = (unsigned short*)alloc((size_t)D * D * sizeof(unsigned short));
    float*          nrm     = (float*)alloc((size_t)N * sizeof(float));
    int*            deg     = (int*)alloc((size_t)N * sizeof(int));
    int*            partial = (int*)alloc((size_t)N * sizeof(int));
    int*            bsum    = (int*)alloc((size_t)SCAN_BLK * sizeof(int));
    int*            row_ptr = (int*)alloc((size_t)(N + 1) * sizeof(int));
    int*            cursor  = (int*)alloc((size_t)N * sizeof(int));
    int*            srcs    = (int*)alloc((size_t)E * sizeof(int));
    (void)ws_size;

    const int NB = (N + SCAN_BLK - 1) / SCAN_BLK;

    cast_wt<<<(D * D + 255) / 256, 256, 0, stream>>>(W, Wt);
    zero_ints<<<(N + 255) / 256, 256, 0, stream>>>(deg, N);
    deg_hist<<<(E + 255) / 256, 256, 0, stream>>>(dst, E, deg);
    scan1<<<NB, SCAN_BLK, 0, stream>>>(deg, N, partial, bsum);
    scan2<<<1, SCAN_BLK, 0, stream>>>(bsum, NB);
    scan3<<<(N + 1 + 255) / 256, 256, 0, stream>>>(partial, bsum, deg, N, E,
                                                   row_ptr, cursor, nrm);
    fill_csr<<<(E + 255) / 256, 256, 0, stream>>>(src, dst, E, cursor, srcs);

    gemm_mfma<<<(N + GBM - 1) / GBM, 512, 0, stream>>>(x, Wt, Hb, N);

    int agg_blocks = (N + 3) / 4;  // 4 waves per 256-thread block
    aggregate_ln<<<agg_blocks, 256, 0, stream>>>(x, Hb, row_ptr, srcs, nrm, bvec,
                                                 gamma, beta, out, N);
}